// Round 1
// baseline (759.068 us; speedup 1.0000x reference)
//
#include <hip/hip_runtime.h>

// ConvNet_STDP — faithful spiking simulation with exact dynamic early-exit.
//
// Key facts derived from the reference (see round-0 analysis):
//  * stdp() never fires (masked pre-reset potentials are strictly < threshold,
//    so their batch mean is too) -> weights are constant; outputs w1/w2 are
//    just clip(w_init, 0, 1).
//  * IAF reset is mask-independent: v resets whenever v >= thr. Mask only
//    gates the *emitted* spike (z2 = z*m), and m_new = m && !z.
//  * Once m2 (layer-2 inhibition mask) is all-zero at the START of a step,
//    z5=z6=z9=0 and h=relu(0+0)=0 for that and all later steps; v1/m1/v2
//    updates can no longer influence any output -> heavy kernels may skip.
//    alive2 counts surviving m2 neurons; `snap` is its step-start snapshot
//    (written by k2 block 0 before gating) so k3/k4 in the dying step still
//    see "alive" and process that step's real spikes.

#define T_STEPS 30
#define BATCH   32
#define H_IN    240
#define W_IN    160
#define C1      4
#define H1      236
#define W1O     156
#define H3      39
#define W3      25
#define C2      20
#define H2      24
#define W2O     10
#define H6      12
#define W6      5
#define C3      10
#define H8      8

#define N_V1   (BATCH*C1*H1*W1O)   // 4,712,448
#define N_V2   (BATCH*C2*H2*W2O)   // 153,600
#define N_V3   (BATCH*C3*H8)       // 2,560
#define N_Z3   (BATCH*C1*H3*W3)    // 124,800
#define N_Z6   (BATCH*C2*H6*W6)    // 38,400
#define N_FEAT (BATCH*C3)          // 320

__global__ __launch_bounds__(256) void k0_init(
    float* v1, float* v2, float* v3, float* lilv,
    unsigned char* m1, unsigned char* m2, unsigned char* m3,
    int* alive2, int* snap,
    const float* __restrict__ w1, const float* __restrict__ w2,
    float* out_w1, float* out_w2)
{
  int gid = blockIdx.x*blockDim.x + threadIdx.x;
  int gsz = gridDim.x*blockDim.x;
  for (int i = gid; i < N_V1; i += gsz) { v1[i] = 0.f; m1[i] = 1; }
  for (int i = gid; i < N_V2; i += gsz) { v2[i] = 0.f; m2[i] = 1; }
  for (int i = gid; i < N_V3; i += gsz) { v3[i] = 0.f; m3[i] = 1; }
  for (int i = gid; i < 20; i += gsz) lilv[i] = 0.f;
  if (gid == 0) { *alive2 = N_V2; *snap = N_V2; }
  // STDP never fires -> final weights are clip(w, 0, 1)
  for (int i = gid; i < C1*25;      i += gsz) out_w1[i] = fminf(fmaxf(w1[i], 0.f), 1.f);
  for (int i = gid; i < C2*C1*256;  i += gsz) out_w2[i] = fminf(fmaxf(w2[i], 0.f), 1.f);
}

// conv1 (1->4, 5x5 VALID) + IAF(thr=10) + lateral-inhibition mask
__global__ __launch_bounds__(256) void k1_conv1(
    const float* __restrict__ x_t, const float* __restrict__ w1,
    float* v1, unsigned char* m1, unsigned char* z2,
    const int* alive2)
{
  if (*alive2 == 0) return;   // m2 dead at step start -> nothing here can reach outputs
  __shared__ float sw[C1*25];
  for (int i = threadIdx.x; i < C1*25; i += blockDim.x) sw[i] = w1[i];
  __syncthreads();
  int gsz = gridDim.x*blockDim.x;
  for (int idx = blockIdx.x*blockDim.x + threadIdx.x; idx < N_V1; idx += gsz) {
    int xw = idx % W1O; int t = idx / W1O;
    int y  = t % H1;    t /= H1;
    int c  = t % C1;    int b = t / C1;
    const float* xp = x_t + (size_t)(b*H_IN + y)*W_IN + xw;
    const float* wp = sw + c*25;
    float s = 0.f;
    #pragma unroll
    for (int i = 0; i < 5; ++i)
      #pragma unroll
      for (int j = 0; j < 5; ++j) s += xp[i*W_IN + j] * wp[i*5 + j];
    float v = v1[idx] + s;
    bool  z = (v >= 10.0f);
    v1[idx] = z ? 0.f : v;            // reset is mask-independent
    unsigned char m = m1[idx];
    unsigned char sp = (z && m) ? 1 : 0;
    z2[idx] = sp;
    if (sp) m1[idx] = 0;
  }
}

// maxpool 7x7 stride 6 over binary spikes = OR. Block 0 also snapshots alive2.
__global__ __launch_bounds__(256) void k2_pool1(
    const unsigned char* __restrict__ z2, unsigned char* z3,
    const int* alive2, int* snap)
{
  if (blockIdx.x == 0 && threadIdx.x == 0) *snap = *alive2;  // pre-gate snapshot
  if (*alive2 == 0) return;
  int gsz = gridDim.x*blockDim.x;
  for (int idx = blockIdx.x*blockDim.x + threadIdx.x; idx < N_Z3; idx += gsz) {
    int px = idx % W3; int t = idx / W3;
    int py = t % H3;   t /= H3;
    int c  = t % C1;   int b = t / C1;
    const unsigned char* p = z2 + ((size_t)(b*C1 + c)*H1 + py*6)*W1O + px*6;
    unsigned char r = 0;
    #pragma unroll
    for (int i = 0; i < 7; ++i)
      #pragma unroll
      for (int j = 0; j < 7; ++j) r |= p[i*W1O + j];
    z3[idx] = r;
  }
}

// conv2 (4->20, 16x16 VALID) + IAF(thr=60) + mask + maxpool 2x2. One block per (b,c2).
__global__ __launch_bounds__(256) void k3_conv2(
    const unsigned char* __restrict__ z3, const float* __restrict__ w2,
    float* v2, unsigned char* m2, unsigned char* z6,
    int* alive2, const int* snap)
{
  if (*snap == 0) return;
  int b = blockIdx.x / C2, c = blockIdx.x % C2;
  __shared__ unsigned char s_in[C1*H3*W3];   // 3900 B
  __shared__ float         s_w[C1*16*16];    // 4 KB
  __shared__ unsigned char s_z5[H2*W2O];     // 240 B
  __shared__ int s_fired;
  for (int i = threadIdx.x; i < C1*H3*W3; i += blockDim.x) s_in[i] = z3[(size_t)b*C1*H3*W3 + i];
  for (int i = threadIdx.x; i < C1*256;   i += blockDim.x) s_w[i]  = w2[(size_t)c*C1*256 + i];
  if (threadIdx.x == 0) s_fired = 0;
  __syncthreads();
  int tid = threadIdx.x;
  if (tid < H2*W2O) {
    int oy = tid / W2O, ox = tid % W2O;
    float s = 0.f;
    for (int ci = 0; ci < C1; ++ci)
      for (int i = 0; i < 16; ++i) {
        const unsigned char* ip = s_in + (ci*H3 + oy + i)*W3 + ox;
        const float* wp = s_w + (ci*16 + i)*16;
        #pragma unroll
        for (int j = 0; j < 16; ++j) if (ip[j]) s += wp[j];
      }
    int gidx = ((b*C2 + c)*H2 + oy)*W2O + ox;
    float v = v2[gidx] + s;
    bool  z = (v >= 60.0f);
    v2[gidx] = z ? 0.f : v;
    unsigned char m = m2[gidx];
    unsigned char sp = (z && m) ? 1 : 0;
    s_z5[tid] = sp;
    if (sp) { m2[gidx] = 0; atomicAdd(&s_fired, 1); }
  }
  __syncthreads();
  if (tid == 0 && s_fired) atomicSub(alive2, s_fired);
  if (tid < H6*W6) {
    int py = tid / W6, px = tid % W6;
    unsigned char r = s_z5[(2*py)*W2O + 2*px]     | s_z5[(2*py)*W2O + 2*px + 1]
                    | s_z5[(2*py+1)*W2O + 2*px]   | s_z5[(2*py+1)*W2O + 2*px + 1];
    z6[((b*C2 + c)*H6 + py)*W6 + px] = r;
  }
}

// conv3 (20->10, 5x5) + IAF(thr=2) + mask + global max -> FC -> LI cell -> volts[t]
__global__ __launch_bounds__(256) void k4_head(
    const unsigned char* __restrict__ z6, const float* __restrict__ w3,
    const float* __restrict__ fc1_w, const float* __restrict__ fc1_b,
    const float* __restrict__ out_w, const float* __restrict__ out_b,
    float* v3, unsigned char* m3, float* li, float* lv,
    float* volts_t, const int* snap)
{
  __shared__ float s_h[64];
  __shared__ float s_feat[N_FEAT];
  __shared__ float s_vnew[16];
  int tid = threadIdx.x;
  bool alive = (*snap != 0);
  if (alive) {
    __shared__ unsigned char s_z6[N_Z6];       // 38,400 B
    __shared__ float         s_w3[C3*C2*25];   // 20 KB
    __shared__ unsigned char s_z8[N_V3];       // 2,560 B
    for (int i = tid; i < N_Z6;     i += 256) s_z6[i] = z6[i];
    for (int i = tid; i < C3*C2*25; i += 256) s_w3[i] = w3[i];
    __syncthreads();
    for (int r = 0; r < N_V3/256; ++r) {
      int idx = tid + 256*r;                   // [B,C3,H8,1]
      int oy = idx % H8; int t2 = idx / H8;
      int c3 = t2 % C3;  int b  = t2 / C3;
      const unsigned char* zb = s_z6 + (size_t)b*C2*H6*W6;
      const float* wp = s_w3 + c3*C2*25;
      float s = 0.f;
      for (int ci = 0; ci < C2; ++ci)
        #pragma unroll
        for (int i = 0; i < 5; ++i) {
          const unsigned char* ip = zb + (ci*H6 + oy + i)*W6;
          const float* w = wp + ci*25 + i*5;
          #pragma unroll
          for (int j = 0; j < 5; ++j) if (ip[j]) s += w[j];
        }
      float v = v3[idx] + s;
      bool  z = (v >= 2.0f);
      v3[idx] = z ? 0.f : v;
      unsigned char m = m3[idx];
      unsigned char sp = (z && m) ? 1 : 0;
      if (sp) m3[idx] = 0;
      s_z8[idx] = sp;
    }
    __syncthreads();
    for (int i = tid; i < N_FEAT; i += 256) {  // z9 = OR over 8 spatial
      const unsigned char* p = s_z8 + i*H8;
      unsigned char r = 0;
      #pragma unroll
      for (int k = 0; k < H8; ++k) r |= p[k];
      s_feat[i] = (float)r;
    }
  } else {
    // m2 was all-zero at step start -> z5=z6=0 -> v3 unchanged (post-reset v3<2
    // guarantees no spikes with zero input) -> feat = 0. Exact.
    for (int i = tid; i < N_FEAT; i += 256) s_feat[i] = 0.f;
  }
  __syncthreads();
  if (tid < 50) {
    float s = 0.f;
    const float* wr = fc1_w + (size_t)tid*N_FEAT;
    for (int j = 0; j < N_FEAT; ++j) s += s_feat[j]*wr[j];
    s += fc1_b[tid];
    s_h[tid] = s > 0.f ? s : 0.f;
  }
  __syncthreads();
  if (tid < C3) {
    float idec = li[tid]*0.8f;                       // 1 - 1e-3*200
    float vnew = lv[tid] + 0.1f*(idec - lv[tid]);    // 1e-3*100
    float acc = idec;
    for (int k = 0; k < 50; ++k) acc += s_h[k]*out_w[tid*50 + k];
    acc += out_b[tid];
    li[tid] = acc;
    lv[tid] = vnew;
    s_vnew[tid] = vnew;
  }
  __syncthreads();
  for (int i = tid; i < N_FEAT; i += 256) volts_t[i] = s_vnew[i % C3];
}

extern "C" void kernel_launch(void* const* d_in, const int* in_sizes, int n_in,
                              void* d_out, int out_size, void* d_ws, size_t ws_size,
                              hipStream_t stream) {
  const float* x      = (const float*)d_in[0];
  const float* w1     = (const float*)d_in[1];
  const float* w2     = (const float*)d_in[2];
  const float* w3     = (const float*)d_in[3];
  const float* fc1_w  = (const float*)d_in[4];
  const float* fc1_b  = (const float*)d_in[5];
  const float* out_w  = (const float*)d_in[6];
  const float* out_b  = (const float*)d_in[7];
  float* out = (float*)d_out;   // [volts 30*32*10 | w1 100 | w2 20480]

  char* p = (char*)d_ws;
  float* v1 = (float*)p;            p += (size_t)N_V1*4;
  float* v2 = (float*)p;            p += (size_t)N_V2*4;
  float* v3 = (float*)p;            p += (size_t)N_V3*4;
  float* lilv = (float*)p;          p += 20*4;          // li[10], lv[10]
  int* alive2 = (int*)p;            p += 4;
  int* snap   = (int*)p;            p += 4;
  unsigned char* m1 = (unsigned char*)p;  p += N_V1;
  unsigned char* m2 = (unsigned char*)p;  p += N_V2;
  unsigned char* m3 = (unsigned char*)p;  p += N_V3;
  unsigned char* z2 = (unsigned char*)p;  p += N_V1;
  unsigned char* z3 = (unsigned char*)p;  p += N_Z3;
  unsigned char* z6 = (unsigned char*)p;  p += N_Z6;

  float* li = lilv;
  float* lv = lilv + 10;

  k0_init<<<512, 256, 0, stream>>>(v1, v2, v3, lilv, m1, m2, m3, alive2, snap,
                                   w1, w2, out + T_STEPS*N_FEAT, out + T_STEPS*N_FEAT + 100);
  for (int t = 0; t < T_STEPS; ++t) {
    const float* x_t = x + (size_t)t * BATCH * H_IN * W_IN;
    k1_conv1<<<2048, 256, 0, stream>>>(x_t, w1, v1, m1, z2, alive2);
    k2_pool1<<<488, 256, 0, stream>>>(z2, z3, alive2, snap);
    k3_conv2<<<BATCH*C2, 256, 0, stream>>>(z3, w2, v2, m2, z6, alive2, snap);
    k4_head<<<1, 256, 0, stream>>>(z6, w3, fc1_w, fc1_b, out_w, out_b,
                                   v3, m3, li, lv, out + (size_t)t*N_FEAT, snap);
  }
}

// Round 2
// 332.514 us; speedup vs baseline: 2.2828x; 2.2828x over previous
//
#include <hip/hip_runtime.h>
#include <hip/hip_cooperative_groups.h>

namespace cg = cooperative_groups;

// ConvNet_STDP — single cooperative kernel, device-side time loop with exact
// dynamic early-exit and closed-form dead-tail.
//
// Facts (verified round 1, absmax 0.0):
//  * STDP never fires (masked pre-reset potentials strictly < threshold, so
//    their batch mean is too) -> weight outputs are clip(w_init, 0, 1).
//  * Once m2 (layer-2 inhibition mask) is all-zero at a step start,
//    z5=z6=z9=0, feat=0, h=relu(fc1_b) for that and all later steps; no
//    remaining state update can reach any output. The LI recurrence becomes
//    li <- 0.8*li + c,  lv <- 0.9*lv + 0.1*(0.8*li),  c = out_b + out_w@relu(fc1_b)
//    -> computed in closed form by the tail (exact, fully general).
//  * IAF reset is mask-independent; mask only gates emitted spikes.

#define T_STEPS 30
#define BATCH   32
#define H_IN    240
#define W_IN    160
#define C1      4
#define H1      236
#define W1O     156
#define H3      39
#define W3      25
#define C2      20
#define H2      24
#define W2O     10
#define H6      12
#define W6      5
#define C3      10
#define H8      8

#define N_V1   (BATCH*C1*H1*W1O)   // 4,712,448
#define N_V2   (BATCH*C2*H2*W2O)   // 153,600
#define N_V3   (BATCH*C3*H8)       // 2,560
#define N_Z3   (BATCH*C1*H3*W3)    // 124,800
#define N_Z6   (BATCH*C2*H6*W6)    // 38,400
#define N_FEAT (BATCH*C3)          // 320

#define NBLK 320
#define NTHR 256

__global__ __launch_bounds__(NTHR, 2) void snn_all(
    const float* __restrict__ x,     const float* __restrict__ w1,
    const float* __restrict__ w2,    const float* __restrict__ w3,
    const float* __restrict__ fc1_w, const float* __restrict__ fc1_b,
    const float* __restrict__ out_w, const float* __restrict__ out_b,
    float* __restrict__ out,
    float* v1, float* v2, float* v3,
    unsigned char* m1, unsigned char* m2, unsigned char* m3,
    unsigned char* z2, unsigned char* z3, unsigned char* z5,
    unsigned char* z6, unsigned char* z8, int* alive2)
{
  cg::grid_group grid = cg::this_grid();
  const int tid = threadIdx.x;
  const int gid = blockIdx.x*NTHR + tid;
  const int gsz = NBLK*NTHR;

  __shared__ float s_w1[C1*25];
  __shared__ float s_feat[N_FEAT];
  __shared__ float s_h[64];
  __shared__ float s_li[10], s_lv[10];
  __shared__ float s_tail[T_STEPS*10];

  // ---- init: weight-clip outputs (STDP provably inert), alive counter, LI state
  float* out_w1 = out + T_STEPS*N_FEAT;
  float* out_w2 = out_w1 + C1*25;
  for (int i = gid; i < C1*25;     i += gsz) out_w1[i] = fminf(fmaxf(w1[i], 0.f), 1.f);
  for (int i = gid; i < C2*C1*256; i += gsz) out_w2[i] = fminf(fmaxf(w2[i], 0.f), 1.f);
  if (gid == 0) *alive2 = N_V2;
  if (blockIdx.x == 0 && tid < 10) { s_li[tid] = 0.f; s_lv[tid] = 0.f; }
  for (int i = tid; i < C1*25; i += NTHR) s_w1[i] = w1[i];
  __syncthreads();

  int t = 0;
  for (; t < T_STEPS; ++t) {
    if (t > 0) {
      // alive2 finalized in stage 3 of step t-1; >=3 grid syncs since.
      int a = __hip_atomic_load(alive2, __ATOMIC_RELAXED, __HIP_MEMORY_SCOPE_AGENT);
      if (a == 0) break;   // uniform across the grid
    }
    const float* xt = x + (size_t)t*BATCH*H_IN*W_IN;

    // ---- stage 1: conv1 (1->4, 5x5) + IAF(10) + lateral-inhibition mask
    for (int idx = gid; idx < N_V1; idx += gsz) {
      int xw = idx % W1O; int tt = idx / W1O;
      int y  = tt % H1;   tt /= H1;
      int c  = tt % C1;   int b = tt / C1;
      const float* xp = xt + (size_t)(b*H_IN + y)*W_IN + xw;
      const float* wp = s_w1 + c*25;
      float s = 0.f;
      #pragma unroll
      for (int i = 0; i < 5; ++i)
        #pragma unroll
        for (int j = 0; j < 5; ++j) s = fmaf(xp[i*W_IN + j], wp[i*5 + j], s);
      float v = (t == 0 ? 0.f : v1[idx]) + s;
      bool  z = (v >= 10.0f);
      v1[idx] = z ? 0.f : v;                       // reset is mask-independent
      unsigned char m  = (t == 0) ? 1 : m1[idx];
      z2[idx] = (z && m) ? 1 : 0;
      m1[idx] = (m && !z) ? 1 : 0;                 // m*(1-z*m) == m && !z
    }
    grid.sync();

    // ---- stage 2: maxpool 7x7 stride 6 over binary spikes = OR
    for (int idx = gid; idx < N_Z3; idx += gsz) {
      int px = idx % W3; int tt = idx / W3;
      int py = tt % H3;  tt /= H3;
      int c  = tt % C1;  int b = tt / C1;
      const unsigned char* p = z2 + ((size_t)(b*C1 + c)*H1 + py*6)*W1O + px*6;
      unsigned char r = 0;
      #pragma unroll
      for (int i = 0; i < 7; ++i)
        #pragma unroll
        for (int j = 0; j < 7; ++j) r |= p[i*W1O + j];
      z3[idx] = r;
    }
    grid.sync();

    // ---- stage 3: conv2 (4->20, 16x16) + IAF(60) + mask + alive accounting
    {
      int nf = 0;
      for (int idx = gid; idx < N_V2; idx += gsz) {
        int ox = idx % W2O; int tt = idx / W2O;
        int oy = tt % H2;   tt /= H2;
        int c  = tt % C2;   int b = tt / C2;
        const unsigned char* zb = z3 + (size_t)b*C1*H3*W3;
        const float* wb = w2 + (size_t)c*C1*256;
        float s = 0.f;
        for (int ci = 0; ci < C1; ++ci)
          for (int i = 0; i < 16; ++i) {
            const unsigned char* ip = zb + (ci*H3 + oy + i)*W3 + ox;
            const float* wp = wb + ci*256 + i*16;
            #pragma unroll
            for (int j = 0; j < 16; ++j) s = fmaf((float)ip[j], wp[j], s);
          }
        float v = (t == 0 ? 0.f : v2[idx]) + s;
        bool  z = (v >= 60.0f);
        v2[idx] = z ? 0.f : v;
        unsigned char m  = (t == 0) ? 1 : m2[idx];
        unsigned char sp = (z && m) ? 1 : 0;
        z5[idx] = sp;
        m2[idx] = (m && !z) ? 1 : 0;
        nf += sp;
      }
      // wave-reduce fired count, one atomic per wave
      #pragma unroll
      for (int o = 1; o < 64; o <<= 1) nf += __shfl_xor(nf, o, 64);
      if ((tid & 63) == 0 && nf) atomicSub(alive2, nf);
    }
    grid.sync();

    // ---- stage 3b: maxpool 2x2 stride 2 = OR
    for (int idx = gid; idx < N_Z6; idx += gsz) {
      int px = idx % W6; int tt = idx / W6;
      int py = tt % H6;  tt /= H6;
      const unsigned char* p = z5 + (size_t)tt*H2*W2O + (2*py)*W2O + 2*px;
      z6[idx] = p[0] | p[1] | p[W2O] | p[W2O+1];
    }
    grid.sync();

    // ---- stage 4: conv3 (20->10, 5x5) + IAF(2) + mask -> z8 spikes
    for (int idx = gid; idx < N_V3; idx += gsz) {
      int oy = idx % H8; int tt = idx / H8;
      int c3 = tt % C3;  int b  = tt / C3;
      const unsigned char* zb = z6 + (size_t)b*C2*H6*W6;
      const float* wb = w3 + (size_t)c3*C2*25;
      float s = 0.f;
      for (int ci = 0; ci < C2; ++ci)
        #pragma unroll
        for (int i = 0; i < 5; ++i) {
          const unsigned char* ip = zb + (ci*H6 + oy + i)*W6;
          const float* wp = wb + ci*25 + i*5;
          #pragma unroll
          for (int j = 0; j < 5; ++j) s = fmaf((float)ip[j], wp[j], s);
        }
      float v = (t == 0 ? 0.f : v3[idx]) + s;
      bool  z = (v >= 2.0f);
      v3[idx] = z ? 0.f : v;
      unsigned char m = (t == 0) ? 1 : m3[idx];
      z8[idx] = (z && m) ? 1 : 0;
      m3[idx] = (m && !z) ? 1 : 0;
    }
    grid.sync();

    // ---- stage 5: feat -> fc1 -> relu -> LI cell -> volts[t]   (block 0 only)
    if (blockIdx.x == 0) {
      for (int i = tid; i < N_FEAT; i += NTHR) {       // z9: OR over 8 spatial
        const unsigned char* p = z8 + i*H8;
        unsigned char r = 0;
        #pragma unroll
        for (int k = 0; k < H8; ++k) r |= p[k];
        s_feat[i] = (float)r;
      }
      __syncthreads();
      {
        int o = tid >> 2, q = tid & 3;                 // 4 lanes per fc1 output
        if (o < 50) {
          const float* wr = fc1_w + (size_t)o*N_FEAT + q*80;
          const float* fr = s_feat + q*80;
          float s = 0.f;
          for (int j = 0; j < 80; ++j) s = fmaf(fr[j], wr[j], s);
          s += __shfl_xor(s, 1, 64);
          s += __shfl_xor(s, 2, 64);
          if (q == 0) s_h[o] = fmaxf(s + fc1_b[o], 0.f);
        }
      }
      __syncthreads();
      if (tid < 10) {
        float idec = s_li[tid]*0.8f;                   // 1 - dt*tau_syn_inv
        float vnew = s_lv[tid] + 0.1f*(idec - s_lv[tid]);
        float acc = idec + out_b[tid];
        for (int k = 0; k < 50; ++k) acc = fmaf(s_h[k], out_w[tid*50 + k], acc);
        s_li[tid] = acc;
        s_lv[tid] = vnew;
      }
      __syncthreads();
      float* vt = out + (size_t)t*N_FEAT;
      for (int i = tid; i < N_FEAT; i += NTHR) vt[i] = s_lv[i % 10];
    }
    grid.sync();
  }

  // ---- closed-form dead tail: h = relu(fc1_b) constant, li/lv scalar decay
  if (t < T_STEPS && blockIdx.x == 0) {
    if (tid < 50) s_h[tid] = fmaxf(fc1_b[tid], 0.f);
    __syncthreads();
    if (tid < 10) {
      float c = out_b[tid];
      for (int k = 0; k < 50; ++k) c = fmaf(s_h[k], out_w[tid*50 + k], c);
      float li = s_li[tid], lv = s_lv[tid];
      for (int tt = t; tt < T_STEPS; ++tt) {
        float idec = li*0.8f;
        lv = lv + 0.1f*(idec - lv);
        li = idec + c;
        s_tail[(tt - t)*10 + tid] = lv;
      }
    }
    __syncthreads();
    int nrem = (T_STEPS - t)*N_FEAT;
    float* vt = out + (size_t)t*N_FEAT;
    for (int i = tid; i < nrem; i += NTHR)
      vt[i] = s_tail[(i/N_FEAT)*10 + (i % 10)];
  }
}

extern "C" void kernel_launch(void* const* d_in, const int* in_sizes, int n_in,
                              void* d_out, int out_size, void* d_ws, size_t ws_size,
                              hipStream_t stream) {
  const float* x      = (const float*)d_in[0];
  const float* w1     = (const float*)d_in[1];
  const float* w2     = (const float*)d_in[2];
  const float* w3     = (const float*)d_in[3];
  const float* fc1_w  = (const float*)d_in[4];
  const float* fc1_b  = (const float*)d_in[5];
  const float* out_w  = (const float*)d_in[6];
  const float* out_b  = (const float*)d_in[7];
  float* out = (float*)d_out;   // [volts 30*320 | w1 100 | w2 20480]

  char* p = (char*)d_ws;
  float* v1 = (float*)p;            p += (size_t)N_V1*4;
  float* v2 = (float*)p;            p += (size_t)N_V2*4;
  float* v3 = (float*)p;            p += (size_t)N_V3*4;
  int* alive2 = (int*)p;            p += 4;
  unsigned char* m1 = (unsigned char*)p;  p += N_V1;
  unsigned char* m2 = (unsigned char*)p;  p += N_V2;
  unsigned char* m3 = (unsigned char*)p;  p += N_V3;
  unsigned char* z2 = (unsigned char*)p;  p += N_V1;
  unsigned char* z3 = (unsigned char*)p;  p += N_Z3;
  unsigned char* z5 = (unsigned char*)p;  p += N_V2;
  unsigned char* z6 = (unsigned char*)p;  p += N_Z6;
  unsigned char* z8 = (unsigned char*)p;  p += N_V3;

  void* args[] = {
    (void*)&x, (void*)&w1, (void*)&w2, (void*)&w3,
    (void*)&fc1_w, (void*)&fc1_b, (void*)&out_w, (void*)&out_b,
    (void*)&out,
    (void*)&v1, (void*)&v2, (void*)&v3,
    (void*)&m1, (void*)&m2, (void*)&m3,
    (void*)&z2, (void*)&z3, (void*)&z5, (void*)&z6, (void*)&z8,
    (void*)&alive2
  };
  hipLaunchCooperativeKernel(reinterpret_cast<void*>(snn_all),
                             dim3(NBLK), dim3(NTHR), args, 0, stream);
}